// Round 11
// baseline (110.572 us; speedup 1.0000x reference)
//
#include <hip/hip_runtime.h>

// AffineGPT2Attention: B=4, S=1024, D=1024, H=16, Dh=64
// Pipeline: cast hs->bf16; transpose+cast weights; QKV GEMM (256^2 tile,
// 8 waves, 4-phase interleaved K-step, dbuf LDS via global_load_lds, counted
// vmcnt, raw s_barrier, setprio); flash attention (4-wave blocks, dbuf LDS);
// proj GEMM (128^2, 2-phase) with bias+affine -> f32 out.

typedef __attribute__((ext_vector_type(4))) float  fx4;
typedef __attribute__((ext_vector_type(4))) short  sx4;
typedef __attribute__((ext_vector_type(8))) short  sx8;
typedef __attribute__((ext_vector_type(4))) float  f32x4;
typedef __attribute__((ext_vector_type(8))) __bf16 bf16x8;

#define DEVI static __device__ __forceinline__

DEVI short f2bf(float f) {  // f32 -> bf16 (RNE)
  unsigned u = __builtin_bit_cast(unsigned, f);
  u = (u + 0x7FFFu + ((u >> 16) & 1u)) >> 16;
  return (short)u;
}

DEVI fx4 mfma16(sx8 a, sx8 b, fx4 c) {
  return __builtin_amdgcn_mfma_f32_16x16x32_bf16(
      __builtin_bit_cast(bf16x8, a), __builtin_bit_cast(bf16x8, b), c, 0, 0, 0);
}

DEVI void gl_lds16(const void* g, void* l) {  // async global->LDS, 16B/lane
  __builtin_amdgcn_global_load_lds(
      (const __attribute__((address_space(1))) void*)g,
      (__attribute__((address_space(3))) void*)l, 16, 0, 0);
}

// ---------------- elementwise f32 -> bf16 cast (vectorized) ----------------
__global__ __launch_bounds__(256) void cast_bf16(const float* __restrict__ in,
                                                 short* __restrict__ out, int n4) {
  int i = blockIdx.x * blockDim.x + threadIdx.x;
  if (i < n4) {
    f32x4 v = *(const f32x4*)&in[(size_t)i * 4];
    sx4 o;
#pragma unroll
    for (int j = 0; j < 4; ++j) o[j] = f2bf(v[j]);
    *(sx4*)&out[(size_t)i * 4] = o;
  }
}

// ---------------- transpose + cast: in[R][C] f32 -> out[C][R] bf16 ----------
__global__ __launch_bounds__(256) void transpose_bf16(const float* __restrict__ in,
                                                      short* __restrict__ out,
                                                      int R, int C) {
  __shared__ float t[32][33];
  int tx = threadIdx.x & 31, ty = threadIdx.x >> 5;
  int r0 = blockIdx.y * 32, c0 = blockIdx.x * 32;
#pragma unroll
  for (int i = 0; i < 4; ++i)
    t[ty + i * 8][tx] = in[(size_t)(r0 + ty + i * 8) * C + c0 + tx];
  __syncthreads();
#pragma unroll
  for (int i = 0; i < 4; ++i)
    out[(size_t)(c0 + ty + i * 8) * R + r0 + tx] = f2bf(t[tx][ty + i * 8]);
}

// ---------------- QKV GEMM: 256^2 tile, 4-phase K-step ----------------------
// C[4096][3072] = A[4096][1024] @ Bt[3072][1024]^T. BM=BN=256, BK=64.
// 512 thr = 8 waves (2M x 4N); wave tile 128x64 = acc[8][4] (64 MFMA/step).
// LDS 128KB dbuf -> 1 block/CU. Per K-step:
//   STAGE(t+1) burst (8 gl_lds/wave) ; vmcnt(8) waits tile t (issued a full
//   step ago) ; s_barrier ; 4 x phase{12 ds_read ; sched_barrier ; s_barrier ;
//   setprio1 ; 16 MFMA (one 4m x 2n quadrant x K=64) ; setprio0 ; s_barrier}.
// Phase-split gives the 8 waves read/MFMA role diversity (T3); counted vmcnt
// keeps next tile's DMA in flight (T4); XOR-swizzled LDS is conflict-free
// (verified 0 in R8-R10); setprio pays only with phase-split (T5).
// Grid 192 = 16bm x 12bn; XCD x owns 4bm x 6bn (~5MB working set).
// Scatter epilogue: Q (pre-scaled 0.125*log2e) / K -> [b,h,s,d], Vt -> [b,h,d,s].
__global__ __launch_bounds__(512, 2) void gemm_qkv(
    const short* __restrict__ A, const short* __restrict__ Bt,
    const float* __restrict__ bias, short* __restrict__ Qg,
    short* __restrict__ Kg, short* __restrict__ Vtg) {
  __shared__ __align__(16) short As[2][256][64];  // 64 KB
  __shared__ __align__(16) short Bs[2][256][64];  // 64 KB
  const int tid = threadIdx.x, lane = tid & 63, w = tid >> 6;
  const int bid = blockIdx.x;
  const int x = bid & 7, k = bid >> 3;            // XCD id, local idx 0..23
  const int bm = (x & 3) * 4 + (k & 3);
  const int bn = (x >> 2) * 6 + (k >> 2);
  const int wm = w >> 2, wn = w & 3;
  const int c0 = lane & 15, g = lane >> 4;
  const int lr8 = lane >> 3;               // row within 8-row staging chunk
  const int ls8 = (lane & 7) ^ lr8;        // inverse-swizzled source slot
  const int K = 1024;
  fx4 acc[8][4] = {};

  auto STAGE = [&](int bf, int kt) {  // 8 gl_lds per wave (4 A + 4 B chunks)
#pragma unroll
    for (int i = 0; i < 4; ++i) {
      int r = w * 32 + i * 8;  // 32 rows per wave
      gl_lds16(&A[(size_t)(bm * 256 + r + lr8) * K + kt + ls8 * 8], &As[bf][r][0]);
      gl_lds16(&Bt[(size_t)(bn * 256 + r + lr8) * K + kt + ls8 * 8], &Bs[bf][r][0]);
    }
  };

  STAGE(0, 0);
  for (int t = 0; t < 16; ++t) {
    const int bf = t & 1;
    if (t + 1 < 16) {
      STAGE(bf ^ 1, (t + 1) * 64);
      asm volatile("s_waitcnt vmcnt(8)" ::: "memory");  // tile t landed
    } else {
      asm volatile("s_waitcnt vmcnt(0)" ::: "memory");
    }
    __builtin_amdgcn_s_barrier();  // all waves: tile t data visible

#pragma unroll
    for (int q = 0; q < 4; ++q) {  // quadrant phases: (m-half, n-half)
      const int m0 = (q >> 1) * 4, n0 = (q & 1) * 2;
      sx8 af[4][2], bfr[2][2];
#pragma unroll
      for (int m = 0; m < 4; ++m) {
        int row = wm * 128 + (m0 + m) * 16 + c0;
#pragma unroll
        for (int kk = 0; kk < 2; ++kk)
          af[m][kk] = *(const sx8*)&As[bf][row][((kk * 4 + g) ^ (row & 7)) * 8];
      }
#pragma unroll
      for (int n = 0; n < 2; ++n) {
        int row = wn * 64 + (n0 + n) * 16 + c0;
#pragma unroll
        for (int kk = 0; kk < 2; ++kk)
          bfr[n][kk] = *(const sx8*)&Bs[bf][row][((kk * 4 + g) ^ (row & 7)) * 8];
      }
      __builtin_amdgcn_sched_barrier(0);  // pin reads before the phase barrier
      __builtin_amdgcn_s_barrier();       // role-alternation barrier
      __builtin_amdgcn_s_setprio(1);
#pragma unroll
      for (int kk = 0; kk < 2; ++kk)
#pragma unroll
        for (int m = 0; m < 4; ++m)
#pragma unroll
          for (int n = 0; n < 2; ++n)
            acc[m0 + m][n0 + n] = mfma16(af[m][kk], bfr[n][kk], acc[m0 + m][n0 + n]);
      __builtin_amdgcn_s_setprio(0);
      __builtin_amdgcn_s_barrier();
    }
  }

  // scatter epilogue (C/D frag layout: row = g*4 + r, col = c0)
  const float SCALE_Q = 0.125f * 1.4426950408889634f;
#pragma unroll
  for (int m = 0; m < 8; ++m) {
#pragma unroll
    for (int n = 0; n < 4; ++n) {
      int col = bn * 256 + wn * 64 + n * 16 + c0;
      int row0 = bm * 256 + wm * 128 + m * 16 + g * 4;
      float bv = bias[col];
      int b = row0 >> 10, s0 = row0 & 1023;
      if (col < 1024) {
        int h = col >> 6, d = col & 63;
        size_t base = ((size_t)(b * 16 + h) * 1024) * 64 + d;
#pragma unroll
        for (int r = 0; r < 4; ++r)
          Qg[base + (size_t)(s0 + r) * 64] = f2bf((acc[m][n][r] + bv) * SCALE_Q);
      } else if (col < 2048) {
        int c = col - 1024, h = c >> 6, d = c & 63;
        size_t base = ((size_t)(b * 16 + h) * 1024) * 64 + d;
#pragma unroll
        for (int r = 0; r < 4; ++r)
          Kg[base + (size_t)(s0 + r) * 64] = f2bf(acc[m][n][r] + bv);
      } else {
        int c = col - 2048, h = c >> 6, d = c & 63;
        sx4 v;
#pragma unroll
        for (int r = 0; r < 4; ++r) v[r] = f2bf(acc[m][n][r] + bv);
        *(sx4*)&Vtg[((size_t)(b * 16 + h) * 64 + d) * 1024 + s0] = v;
      }
    }
  }
}

// ---------------- proj GEMM: 128^2 tile, 2-phase (unchanged) ----------------
__global__ __launch_bounds__(512, 4) void gemm_proj(
    const short* __restrict__ A, const short* __restrict__ Bt,
    const float* __restrict__ bias, const float* __restrict__ aw,
    const float* __restrict__ ab, float* __restrict__ Out) {
  __shared__ __align__(16) short As[2][128][64];  // 32 KB
  __shared__ __align__(16) short Bs[2][128][64];  // 32 KB
  const int tid = threadIdx.x, lane = tid & 63, w = tid >> 6;
  const int bid = blockIdx.x;
  const int x = bid & 7, k = bid >> 3;
  const int bn = x + 0 * 8, bm = k;  // nbn=8: one bn column per XCD
  const int wm = w >> 2, wn = w & 3;
  const int c0 = lane & 15, g = lane >> 4;
  const int lr8 = lane >> 3, ls8 = (lane & 7) ^ lr8;
  const int K = 1024, N = 1024;
  fx4 acc[4][2] = {};

  auto STAGE = [&](int bf, int kt) {
#pragma unroll
    for (int i = 0; i < 2; ++i) {
      int idx = w * 2 + i;
      gl_lds16(&A[(size_t)(bm * 128 + idx * 8 + lr8) * K + kt + ls8 * 8],
               &As[bf][idx * 8][0]);
      gl_lds16(&Bt[(size_t)(bn * 128 + idx * 8 + lr8) * K + kt + ls8 * 8],
               &Bs[bf][idx * 8][0]);
    }
  };

  STAGE(0, 0);
  for (int t = 0; t < 16; ++t) {
    const int bf = t & 1;
    if (t + 1 < 16) {
      STAGE(bf ^ 1, (t + 1) * 64);
      asm volatile("s_waitcnt vmcnt(4)" ::: "memory");
    } else {
      asm volatile("s_waitcnt vmcnt(0)" ::: "memory");
    }
    __builtin_amdgcn_s_barrier();
    __builtin_amdgcn_s_setprio(1);
#pragma unroll
    for (int kk = 0; kk < 2; ++kk) {
      sx8 af[4], bfr[2];
      int sb = kk * 4 + g;
#pragma unroll
      for (int m = 0; m < 4; ++m) {
        int row = wm * 64 + m * 16 + c0;
        af[m] = *(const sx8*)&As[bf][row][(sb ^ (row & 7)) * 8];
      }
#pragma unroll
      for (int n = 0; n < 2; ++n) {
        int row = wn * 32 + n * 16 + c0;
        bfr[n] = *(const sx8*)&Bs[bf][row][(sb ^ (row & 7)) * 8];
      }
#pragma unroll
      for (int m = 0; m < 4; ++m)
#pragma unroll
        for (int n = 0; n < 2; ++n) acc[m][n] = mfma16(af[m], bfr[n], acc[m][n]);
    }
    __builtin_amdgcn_s_setprio(0);
    __builtin_amdgcn_s_barrier();
  }

#pragma unroll
  for (int m = 0; m < 4; ++m) {
#pragma unroll
    for (int n = 0; n < 2; ++n) {
      int col = bn * 128 + wn * 32 + n * 16 + c0;
      int row0 = bm * 128 + wm * 64 + m * 16 + g * 4;
      float bv = bias[col], wv = aw[col], av = ab[col];
#pragma unroll
      for (int r = 0; r < 4; ++r)
        Out[(size_t)(row0 + r) * N + col] = (acc[m][n][r] + bv) * wv + av;
    }
  }
}

// ---------------- flash attention (causal), LDS-staged K/V ------------------
__global__ __launch_bounds__(256, 4) void attn_kernel(const short* __restrict__ Qg,
                                                      const short* __restrict__ Kg,
                                                      const short* __restrict__ Vtg,
                                                      short* __restrict__ AO) {
  __shared__ __align__(16) short Ks[2][64][64];   // 16 KB
  __shared__ __align__(16) short Vts[2][64][64];  // 16 KB
  __shared__ __align__(16) short Ps[4][16 * 64];  // 8 KB
  const int tid = threadIdx.x, lane = tid & 63, w = tid >> 6;
  const int bid = blockIdx.x;
  const int u = bid >> 8, v = bid & 255, bh = v >> 2, jj = v & 3;
  const int qt = (u == 0) ? jj : (u == 1) ? 7 - jj : (u == 2) ? 8 + jj : 15 - jj;
  const int b = bh >> 4, h = bh & 15;
  const int c0 = lane & 15, g = lane >> 4;
  const int lr8 = lane >> 3, ls8 = (lane & 7) ^ lr8;
  const int q0 = qt * 64 + w * 16;
  const short* Qp = Qg + (size_t)bh * 65536;
  const short* Kp = Kg + (size_t)bh * 65536;
  const short* Vp = Vtg + (size_t)bh * 65536;
  short* pbase = &Ps[w][0];
  const int s8 = (c0 & 7) * 8;  // P swizzle

  sx8 qf[2];
#pragma unroll
  for (int kk = 0; kk < 2; ++kk)
    qf[kk] = *(const sx8*)&Qp[(size_t)(q0 + c0) * 64 + kk * 32 + g * 8];

  fx4 o[4] = {};
  float mrun = -1e30f, lrun = 0.f;
  const int q_glob = q0 + c0;

  auto STAGE = [&](int bf, int kv0) {
#pragma unroll
    for (int i = 0; i < 2; ++i) {
      int idx = w * 2 + i;
      gl_lds16(&Kp[(size_t)(kv0 + idx * 8 + lr8) * 64 + ls8 * 8], &Ks[bf][idx * 8][0]);
    }
#pragma unroll
    for (int i = 0; i < 2; ++i) {
      int idx = w * 2 + i;
      gl_lds16(&Vp[(size_t)(idx * 8 + lr8) * 1024 + kv0 + ls8 * 8], &Vts[bf][idx * 8][0]);
    }
  };

  STAGE(0, 0);
  for (int t = 0; t <= qt; ++t) {
    const int kv0 = t * 64;
    const int bf = t & 1;
    const bool more = t < qt;
    if (more) {
      STAGE(bf ^ 1, kv0 + 64);
      asm volatile("s_waitcnt vmcnt(4)" ::: "memory");
    } else {
      asm volatile("s_waitcnt vmcnt(0)" ::: "memory");
    }
    __builtin_amdgcn_s_barrier();

    fx4 st[4];
    __builtin_amdgcn_s_setprio(1);
#pragma unroll
    for (int mf = 0; mf < 4; ++mf) {
      int row = mf * 16 + c0;
      sx8 kf0 = *(const sx8*)&Ks[bf][row][(g ^ (row & 7)) * 8];
      sx8 kf1 = *(const sx8*)&Ks[bf][row][((4 + g) ^ (row & 7)) * 8];
      fx4 z = {0.f, 0.f, 0.f, 0.f};
      z = mfma16(kf0, qf[0], z);
      st[mf] = mfma16(kf1, qf[1], z);
    }
    __builtin_amdgcn_s_setprio(0);

    float pmax = -1e30f;
    if (t == qt) {
#pragma unroll
      for (int mf = 0; mf < 4; ++mf)
#pragma unroll
        for (int r = 0; r < 4; ++r) {
          int kv = kv0 + mf * 16 + g * 4 + r;
          float z = (kv > q_glob) ? -1e30f : st[mf][r];
          st[mf][r] = z;
          pmax = fmaxf(pmax, z);
        }
    } else {
#pragma unroll
      for (int mf = 0; mf < 4; ++mf)
#pragma unroll
        for (int r = 0; r < 4; ++r) pmax = fmaxf(pmax, st[mf][r]);
    }
    pmax = fmaxf(pmax, __shfl_xor(pmax, 16));
    pmax = fmaxf(pmax, __shfl_xor(pmax, 32));
    float mnew = fmaxf(mrun, pmax);
    float alpha = __builtin_amdgcn_exp2f(mrun - mnew);
    float psum = 0.f;
#pragma unroll
    for (int mf = 0; mf < 4; ++mf) {
      sx4 pv;
#pragma unroll
      for (int r = 0; r < 4; ++r) {
        float pp = __builtin_amdgcn_exp2f(st[mf][r] - mnew);
        psum += pp;
        pv[r] = f2bf(pp);
      }
      *(sx4*)&pbase[c0 * 64 + ((mf * 16 + g * 4) ^ s8)] = pv;
    }
    psum += __shfl_xor(psum, 16);
    psum += __shfl_xor(psum, 32);
    lrun = lrun * alpha + psum;
    mrun = mnew;
#pragma unroll
    for (int mf = 0; mf < 4; ++mf) o[mf] *= alpha;

    __builtin_amdgcn_s_setprio(1);
#pragma unroll
    for (int kk = 0; kk < 2; ++kk) {
      sx8 pbf = *(const sx8*)&pbase[c0 * 64 + ((kk * 32 + g * 8) ^ s8)];
#pragma unroll
      for (int mf = 0; mf < 4; ++mf) {
        int row = mf * 16 + c0;
        sx8 vaf = *(const sx8*)&Vts[bf][row][((kk * 4 + g) ^ (row & 7)) * 8];
        o[mf] = mfma16(vaf, pbf, o[mf]);
      }
    }
    __builtin_amdgcn_s_setprio(0);
    __builtin_amdgcn_s_barrier();
  }

  float inv = 1.0f / lrun;
  int q = q0 + c0;
#pragma unroll
  for (int mf = 0; mf < 4; ++mf) {
    sx4 v4;
#pragma unroll
    for (int r = 0; r < 4; ++r) v4[r] = f2bf(o[mf][r] * inv);
    int d0 = mf * 16 + g * 4;
    *(sx4*)&AO[((size_t)(b * 1024 + q)) * 1024 + h * 64 + d0] = v4;
  }
}

// ---------------- launch ----------------------------------------------------
extern "C" void kernel_launch(void* const* d_in, const int* in_sizes, int n_in,
                              void* d_out, int out_size, void* d_ws, size_t ws_size,
                              hipStream_t stream) {
  const float* hs  = (const float*)d_in[0];
  const float* caw = (const float*)d_in[1];
  const float* cab = (const float*)d_in[2];
  const float* cpw = (const float*)d_in[3];
  const float* cpb = (const float*)d_in[4];
  const float* afw = (const float*)d_in[5];
  const float* afb = (const float*)d_in[6];
  float* out = (float*)d_out;
  char* ws = (char*)d_ws;

  short* hsb    = (short*)(ws);                       // [4096][1024] bf16
  short* ao     = (short*)(ws);                       // overlaps hsb
  short* wqkvt  = (short*)(ws + ((size_t)8  << 20));  // [3072][1024] bf16
  short* wprojt = (short*)(ws + ((size_t)14 << 20));  // [1024][1024] bf16
  short* Qg     = (short*)(ws + ((size_t)16 << 20));  // [4][16][1024][64]
  short* Kg     = (short*)(ws + ((size_t)24 << 20));  // [4][16][1024][64]
  short* Vtg    = (short*)(ws + ((size_t)32 << 20));  // [4][16][64][1024]

  cast_bf16<<<4096, 256, 0, stream>>>(hs, hsb, 1048576);
  transpose_bf16<<<dim3(96, 32), 256, 0, stream>>>(caw, wqkvt, 1024, 3072);
  transpose_bf16<<<dim3(32, 32), 256, 0, stream>>>(cpw, wprojt, 1024, 1024);
  gemm_qkv<<<192, 512, 0, stream>>>(hsb, wqkvt, cab, Qg, Kg, Vtg);
  attn_kernel<<<1024, 256, 0, stream>>>(Qg, Kg, Vtg, ao);
  gemm_proj<<<256, 512, 0, stream>>>(ao, wprojt, cpb, afw, afb, out);
}

// Round 12
// 109.954 us; speedup vs baseline: 1.0056x; 1.0056x over previous
//
#include <hip/hip_runtime.h>

// AffineGPT2Attention: B=4, S=1024, D=1024, H=16, Dh=64
// Pipeline: cast hs->bf16; transpose+cast weights; QKV GEMM (256^2 tile, BK=32,
// 8 waves, 2-barrier K-step, dbuf LDS via global_load_lds, counted vmcnt);
// flash attention (4-wave blocks, dbuf LDS); proj GEMM (128^2) -> f32 out.

typedef __attribute__((ext_vector_type(4))) float  fx4;
typedef __attribute__((ext_vector_type(4))) short  sx4;
typedef __attribute__((ext_vector_type(8))) short  sx8;
typedef __attribute__((ext_vector_type(4))) float  f32x4;
typedef __attribute__((ext_vector_type(8))) __bf16 bf16x8;

#define DEVI static __device__ __forceinline__

DEVI short f2bf(float f) {  // f32 -> bf16 (RNE)
  unsigned u = __builtin_bit_cast(unsigned, f);
  u = (u + 0x7FFFu + ((u >> 16) & 1u)) >> 16;
  return (short)u;
}

DEVI fx4 mfma16(sx8 a, sx8 b, fx4 c) {
  return __builtin_amdgcn_mfma_f32_16x16x32_bf16(
      __builtin_bit_cast(bf16x8, a), __builtin_bit_cast(bf16x8, b), c, 0, 0, 0);
}

DEVI void gl_lds16(const void* g, void* l) {  // async global->LDS, 16B/lane
  __builtin_amdgcn_global_load_lds(
      (const __attribute__((address_space(1))) void*)g,
      (__attribute__((address_space(3))) void*)l, 16, 0, 0);
}

// ---------------- elementwise f32 -> bf16 cast (vectorized) ----------------
__global__ __launch_bounds__(256) void cast_bf16(const float* __restrict__ in,
                                                 short* __restrict__ out, int n4) {
  int i = blockIdx.x * blockDim.x + threadIdx.x;
  if (i < n4) {
    f32x4 v = *(const f32x4*)&in[(size_t)i * 4];
    sx4 o;
#pragma unroll
    for (int j = 0; j < 4; ++j) o[j] = f2bf(v[j]);
    *(sx4*)&out[(size_t)i * 4] = o;
  }
}

// ---------------- transpose + cast: in[R][C] f32 -> out[C][R] bf16 ----------
__global__ __launch_bounds__(256) void transpose_bf16(const float* __restrict__ in,
                                                      short* __restrict__ out,
                                                      int R, int C) {
  __shared__ float t[32][33];
  int tx = threadIdx.x & 31, ty = threadIdx.x >> 5;
  int r0 = blockIdx.y * 32, c0 = blockIdx.x * 32;
#pragma unroll
  for (int i = 0; i < 4; ++i)
    t[ty + i * 8][tx] = in[(size_t)(r0 + ty + i * 8) * C + c0 + tx];
  __syncthreads();
#pragma unroll
  for (int i = 0; i < 4; ++i)
    out[(size_t)(c0 + ty + i * 8) * R + r0 + tx] = f2bf(t[tx][ty + i * 8]);
}

// ---------------- QKV GEMM: 256^2 tile, BK=32, 2-barrier K-step -------------
// C[4096][3072] = A[4096][1024] @ Bt[3072][1024]^T. BM=BN=256, BK=32.
// 512 thr = 8 waves (2M x 4N); wave tile 128x64 = acc[8][4]; per K-step each
// wave does exactly 12 ds_read_b128 (8 A + 4 B, the minimum) for 32 MFMA —
// 0.375 reads/MFMA (R10: 0.75; R11's quadrant phases: 0.75 + 9 barriers).
// Schedule = the PROVEN 2-barrier loop (R7/R10): STAGE(t+1) burst (4 gl_lds);
// vmcnt(4) (tile t's loads issued a full step ago -> ~free); s_barrier;
// compiler-interleaved ds_read+MFMA; s_barrier. 64KB LDS dbuf.
// 256^2 halves staged volume vs 128^2: 192MB total (the R10 binder).
// LDS layout [256][32] with 16B-slot XOR swizzle slot^=((row^(row>>2))&3):
// read pattern <=2-way bank aliasing (free); gl_lds writes linear with
// pre-swizzled global source (both-sides-or-neither rule).
// Grid 192 = 16bm x 12bn; XCD x owns 4bm x 6bn (FETCH 20.7MB verified R11).
__global__ __launch_bounds__(512, 2) void gemm_qkv(
    const short* __restrict__ A, const short* __restrict__ Bt,
    const float* __restrict__ bias, short* __restrict__ Qg,
    short* __restrict__ Kg, short* __restrict__ Vtg) {
  __shared__ __align__(16) short As[2][256][32];  // 32 KB
  __shared__ __align__(16) short Bs[2][256][32];  // 32 KB
  const int tid = threadIdx.x, lane = tid & 63, w = tid >> 6;
  const int bid = blockIdx.x;
  const int x = bid & 7, k = bid >> 3;            // XCD id, local idx 0..23
  const int bm = (x & 3) * 4 + (k & 3);
  const int bn = (x >> 2) * 6 + (k >> 2);
  const int wm = w >> 2, wn = w & 3;              // wave tile: 128 rows x 64 cols
  const int c0 = lane & 15, g = lane >> 4;
  const int lr16 = lane >> 2;                     // row within 16-row DMA chunk
  const int xs = (lr16 ^ (lr16 >> 2)) & 3;        // swizzle of this lane's row
  const int src_slot = (lane & 3) ^ xs;           // pre-swizzled global 16B slot
  const int K = 1024;
  fx4 acc[8][4] = {};

  auto STAGE = [&](int bf, int kt) {  // 4 gl_lds per thread (2 A + 2 B chunks)
#pragma unroll
    for (int i = 0; i < 2; ++i) {
      int ch = w * 2 + i;  // 16-row chunk, 16 chunks per matrix
      int row = ch * 16 + lr16;
      gl_lds16(&A[(size_t)(bm * 256 + row) * K + kt + src_slot * 8], &As[bf][ch * 16][0]);
      gl_lds16(&Bt[(size_t)(bn * 256 + row) * K + kt + src_slot * 8], &Bs[bf][ch * 16][0]);
    }
  };

  STAGE(0, 0);
  for (int t = 0; t < 32; ++t) {
    const int bf = t & 1;
    if (t + 1 < 32) {
      STAGE(bf ^ 1, (t + 1) * 32);
      asm volatile("s_waitcnt vmcnt(4)" ::: "memory");  // tile t landed
    } else {
      asm volatile("s_waitcnt vmcnt(0)" ::: "memory");
    }
    __builtin_amdgcn_s_barrier();  // raw: next tile's DMA stays in flight

    sx8 af[8], bfr[4];
#pragma unroll
    for (int m = 0; m < 8; ++m) {
      int row = wm * 128 + m * 16 + c0;
      af[m] = *(const sx8*)&As[bf][row][(g ^ ((row ^ (row >> 2)) & 3)) * 8];
    }
#pragma unroll
    for (int n = 0; n < 4; ++n) {
      int row = wn * 64 + n * 16 + c0;
      bfr[n] = *(const sx8*)&Bs[bf][row][(g ^ ((row ^ (row >> 2)) & 3)) * 8];
    }
    __builtin_amdgcn_s_setprio(1);
#pragma unroll
    for (int m = 0; m < 8; ++m)
#pragma unroll
      for (int n = 0; n < 4; ++n) acc[m][n] = mfma16(af[m], bfr[n], acc[m][n]);
    __builtin_amdgcn_s_setprio(0);
    __builtin_amdgcn_s_barrier();  // buffer-rotation safety
  }

  // scatter epilogue (C/D frag layout: row = g*4 + r, col = c0)
  const float SCALE_Q = 0.125f * 1.4426950408889634f;
#pragma unroll
  for (int m = 0; m < 8; ++m) {
#pragma unroll
    for (int n = 0; n < 4; ++n) {
      int col = bn * 256 + wn * 64 + n * 16 + c0;
      int row0 = bm * 256 + wm * 128 + m * 16 + g * 4;
      float bv = bias[col];
      int b = row0 >> 10, s0 = row0 & 1023;
      if (col < 1024) {
        int h = col >> 6, d = col & 63;
        size_t base = ((size_t)(b * 16 + h) * 1024) * 64 + d;
#pragma unroll
        for (int r = 0; r < 4; ++r)
          Qg[base + (size_t)(s0 + r) * 64] = f2bf((acc[m][n][r] + bv) * SCALE_Q);
      } else if (col < 2048) {
        int c = col - 1024, h = c >> 6, d = c & 63;
        size_t base = ((size_t)(b * 16 + h) * 1024) * 64 + d;
#pragma unroll
        for (int r = 0; r < 4; ++r)
          Kg[base + (size_t)(s0 + r) * 64] = f2bf(acc[m][n][r] + bv);
      } else {
        int c = col - 2048, h = c >> 6, d = c & 63;
        sx4 v;
#pragma unroll
        for (int r = 0; r < 4; ++r) v[r] = f2bf(acc[m][n][r] + bv);
        *(sx4*)&Vtg[((size_t)(b * 16 + h) * 64 + d) * 1024 + s0] = v;
      }
    }
  }
}

// ---------------- proj GEMM: 128^2 tile, 2-phase (unchanged) ----------------
__global__ __launch_bounds__(512, 4) void gemm_proj(
    const short* __restrict__ A, const short* __restrict__ Bt,
    const float* __restrict__ bias, const float* __restrict__ aw,
    const float* __restrict__ ab, float* __restrict__ Out) {
  __shared__ __align__(16) short As[2][128][64];  // 32 KB
  __shared__ __align__(16) short Bs[2][128][64];  // 32 KB
  const int tid = threadIdx.x, lane = tid & 63, w = tid >> 6;
  const int bid = blockIdx.x;
  const int x = bid & 7, k = bid >> 3;
  const int bn = x, bm = k;  // nbn=8: one bn column per XCD
  const int wm = w >> 2, wn = w & 3;
  const int c0 = lane & 15, g = lane >> 4;
  const int lr8 = lane >> 3, ls8 = (lane & 7) ^ lr8;
  const int K = 1024, N = 1024;
  fx4 acc[4][2] = {};

  auto STAGE = [&](int bf, int kt) {
#pragma unroll
    for (int i = 0; i < 2; ++i) {
      int idx = w * 2 + i;
      gl_lds16(&A[(size_t)(bm * 128 + idx * 8 + lr8) * K + kt + ls8 * 8],
               &As[bf][idx * 8][0]);
      gl_lds16(&Bt[(size_t)(bn * 128 + idx * 8 + lr8) * K + kt + ls8 * 8],
               &Bs[bf][idx * 8][0]);
    }
  };

  STAGE(0, 0);
  for (int t = 0; t < 16; ++t) {
    const int bf = t & 1;
    if (t + 1 < 16) {
      STAGE(bf ^ 1, (t + 1) * 64);
      asm volatile("s_waitcnt vmcnt(4)" ::: "memory");
    } else {
      asm volatile("s_waitcnt vmcnt(0)" ::: "memory");
    }
    __builtin_amdgcn_s_barrier();
    __builtin_amdgcn_s_setprio(1);
#pragma unroll
    for (int kk = 0; kk < 2; ++kk) {
      sx8 af[4], bfr[2];
      int sb = kk * 4 + g;
#pragma unroll
      for (int m = 0; m < 4; ++m) {
        int row = wm * 64 + m * 16 + c0;
        af[m] = *(const sx8*)&As[bf][row][(sb ^ (row & 7)) * 8];
      }
#pragma unroll
      for (int n = 0; n < 2; ++n) {
        int row = wn * 32 + n * 16 + c0;
        bfr[n] = *(const sx8*)&Bs[bf][row][(sb ^ (row & 7)) * 8];
      }
#pragma unroll
      for (int m = 0; m < 4; ++m)
#pragma unroll
        for (int n = 0; n < 2; ++n) acc[m][n] = mfma16(af[m], bfr[n], acc[m][n]);
    }
    __builtin_amdgcn_s_setprio(0);
    __builtin_amdgcn_s_barrier();
  }

#pragma unroll
  for (int m = 0; m < 4; ++m) {
#pragma unroll
    for (int n = 0; n < 2; ++n) {
      int col = bn * 128 + wn * 32 + n * 16 + c0;
      int row0 = bm * 128 + wm * 64 + m * 16 + g * 4;
      float bv = bias[col], wv = aw[col], av = ab[col];
#pragma unroll
      for (int r = 0; r < 4; ++r)
        Out[(size_t)(row0 + r) * N + col] = (acc[m][n][r] + bv) * wv + av;
    }
  }
}

// ---------------- flash attention (causal), LDS-staged K/V ------------------
__global__ __launch_bounds__(256, 4) void attn_kernel(const short* __restrict__ Qg,
                                                      const short* __restrict__ Kg,
                                                      const short* __restrict__ Vtg,
                                                      short* __restrict__ AO) {
  __shared__ __align__(16) short Ks[2][64][64];   // 16 KB
  __shared__ __align__(16) short Vts[2][64][64];  // 16 KB
  __shared__ __align__(16) short Ps[4][16 * 64];  // 8 KB
  const int tid = threadIdx.x, lane = tid & 63, w = tid >> 6;
  const int bid = blockIdx.x;
  const int u = bid >> 8, v = bid & 255, bh = v >> 2, jj = v & 3;
  const int qt = (u == 0) ? jj : (u == 1) ? 7 - jj : (u == 2) ? 8 + jj : 15 - jj;
  const int b = bh >> 4, h = bh & 15;
  const int c0 = lane & 15, g = lane >> 4;
  const int lr8 = lane >> 3, ls8 = (lane & 7) ^ lr8;
  const int q0 = qt * 64 + w * 16;
  const short* Qp = Qg + (size_t)bh * 65536;
  const short* Kp = Kg + (size_t)bh * 65536;
  const short* Vp = Vtg + (size_t)bh * 65536;
  short* pbase = &Ps[w][0];
  const int s8 = (c0 & 7) * 8;  // P swizzle

  sx8 qf[2];
#pragma unroll
  for (int kk = 0; kk < 2; ++kk)
    qf[kk] = *(const sx8*)&Qp[(size_t)(q0 + c0) * 64 + kk * 32 + g * 8];

  fx4 o[4] = {};
  float mrun = -1e30f, lrun = 0.f;
  const int q_glob = q0 + c0;

  auto STAGE = [&](int bf, int kv0) {
#pragma unroll
    for (int i = 0; i < 2; ++i) {
      int idx = w * 2 + i;
      gl_lds16(&Kp[(size_t)(kv0 + idx * 8 + lr8) * 64 + ls8 * 8], &Ks[bf][idx * 8][0]);
    }
#pragma unroll
    for (int i = 0; i < 2; ++i) {
      int idx = w * 2 + i;
      gl_lds16(&Vp[(size_t)(idx * 8 + lr8) * 1024 + kv0 + ls8 * 8], &Vts[bf][idx * 8][0]);
    }
  };

  STAGE(0, 0);
  for (int t = 0; t <= qt; ++t) {
    const int kv0 = t * 64;
    const int bf = t & 1;
    const bool more = t < qt;
    if (more) {
      STAGE(bf ^ 1, kv0 + 64);
      asm volatile("s_waitcnt vmcnt(4)" ::: "memory");
    } else {
      asm volatile("s_waitcnt vmcnt(0)" ::: "memory");
    }
    __builtin_amdgcn_s_barrier();

    fx4 st[4];
    __builtin_amdgcn_s_setprio(1);
#pragma unroll
    for (int mf = 0; mf < 4; ++mf) {
      int row = mf * 16 + c0;
      sx8 kf0 = *(const sx8*)&Ks[bf][row][(g ^ (row & 7)) * 8];
      sx8 kf1 = *(const sx8*)&Ks[bf][row][((4 + g) ^ (row & 7)) * 8];
      fx4 z = {0.f, 0.f, 0.f, 0.f};
      z = mfma16(kf0, qf[0], z);
      st[mf] = mfma16(kf1, qf[1], z);
    }
    __builtin_amdgcn_s_setprio(0);

    float pmax = -1e30f;
    if (t == qt) {
#pragma unroll
      for (int mf = 0; mf < 4; ++mf)
#pragma unroll
        for (int r = 0; r < 4; ++r) {
          int kv = kv0 + mf * 16 + g * 4 + r;
          float z = (kv > q_glob) ? -1e30f : st[mf][r];
          st[mf][r] = z;
          pmax = fmaxf(pmax, z);
        }
    } else {
#pragma unroll
      for (int mf = 0; mf < 4; ++mf)
#pragma unroll
        for (int r = 0; r < 4; ++r) pmax = fmaxf(pmax, st[mf][r]);
    }
    pmax = fmaxf(pmax, __shfl_xor(pmax, 16));
    pmax = fmaxf(pmax, __shfl_xor(pmax, 32));
    float mnew = fmaxf(mrun, pmax);
    float alpha = __builtin_amdgcn_exp2f(mrun - mnew);
    float psum = 0.f;
#pragma unroll
    for (int mf = 0; mf < 4; ++mf) {
      sx4 pv;
#pragma unroll
      for (int r = 0; r < 4; ++r) {
        float pp = __builtin_amdgcn_exp2f(st[mf][r] - mnew);
        psum += pp;
        pv[r] = f2bf(pp);
      }
      *(sx4*)&pbase[c0 * 64 + ((mf * 16 + g * 4) ^ s8)] = pv;
    }
    psum += __shfl_xor(psum, 16);
    psum += __shfl_xor(psum, 32);
    lrun = lrun * alpha + psum;
    mrun = mnew;
#pragma unroll
    for (int mf = 0; mf < 4; ++mf) o[mf] *= alpha;

    __builtin_amdgcn_s_setprio(1);
#pragma unroll
    for (int kk = 0; kk < 2; ++kk) {
      sx8 pbf = *(const sx8*)&pbase[c0 * 64 + ((kk * 32 + g * 8) ^ s8)];
#pragma unroll
      for (int mf = 0; mf < 4; ++mf) {
        int row = mf * 16 + c0;
        sx8 vaf = *(const sx8*)&Vts[bf][row][((kk * 4 + g) ^ (row & 7)) * 8];
        o[mf] = mfma16(vaf, pbf, o[mf]);
      }
    }
    __builtin_amdgcn_s_setprio(0);
    __builtin_amdgcn_s_barrier();
  }

  float inv = 1.0f / lrun;
  int q = q0 + c0;
#pragma unroll
  for (int mf = 0; mf < 4; ++mf) {
    sx4 v4;
#pragma unroll
    for (int r = 0; r < 4; ++r) v4[r] = f2bf(o[mf][r] * inv);
    int d0 = mf * 16 + g * 4;
    *(sx4*)&AO[((size_t)(b * 1024 + q)) * 1024 + h * 64 + d0] = v4;
  }
}

// ---------------- launch ----------------------------------------------------
extern "C" void kernel_launch(void* const* d_in, const int* in_sizes, int n_in,
                              void* d_out, int out_size, void* d_ws, size_t ws_size,
                              hipStream_t stream) {
  const float* hs  = (const float*)d_in[0];
  const float* caw = (const float*)d_in[1];
  const float* cab = (const float*)d_in[2];
  const float* cpw = (const float*)d_in[3];
  const float* cpb = (const float*)d_in[4];
  const float* afw = (const float*)d_in[5];
  const float* afb = (const float*)d_in[6];
  float* out = (float*)d_out;
  char* ws = (char*)d_ws;

  short* hsb    = (short*)(ws);                       // [4096][1024] bf16
  short* ao     = (short*)(ws);                       // overlaps hsb
  short* wqkvt  = (short*)(ws + ((size_t)8  << 20));  // [3072][1024] bf16
  short* wprojt = (short*)(ws + ((size_t)14 << 20));  // [1024][1024] bf16
  short* Qg     = (short*)(ws + ((size_t)16 << 20));  // [4][16][1024][64]
  short* Kg     = (short*)(ws + ((size_t)24 << 20));  // [4][16][1024][64]
  short* Vtg    = (short*)(ws + ((size_t)32 << 20));  // [4][16][64][1024]

  cast_bf16<<<4096, 256, 0, stream>>>(hs, hsb, 1048576);
  transpose_bf16<<<dim3(96, 32), 256, 0, stream>>>(caw, wqkvt, 1024, 3072);
  transpose_bf16<<<dim3(32, 32), 256, 0, stream>>>(cpw, wprojt, 1024, 1024);
  gemm_qkv<<<192, 512, 0, stream>>>(hsb, wqkvt, cab, Qg, Kg, Vtg);
  attn_kernel<<<1024, 256, 0, stream>>>(Qg, Kg, Vtg, ao);
  gemm_proj<<<256, 512, 0, stream>>>(ao, wprojt, cpb, afw, afb, out);
}

// Round 13
// 97.570 us; speedup vs baseline: 1.1333x; 1.1269x over previous
//
#include <hip/hip_runtime.h>

// AffineGPT2Attention: B=4, S=1024, D=1024, H=16, Dh=64
// QKV GEMM = m201-style 256^2 8-phase template (4 phases/K-tile, 1 half-tile
// staged per phase, counted vmcnt once per K-tile, setprio, 0-conflict
// [*][64] XOR swizzle). attn/proj/prologue unchanged from R12.

typedef __attribute__((ext_vector_type(4))) float  fx4;
typedef __attribute__((ext_vector_type(4))) short  sx4;
typedef __attribute__((ext_vector_type(8))) short  sx8;
typedef __attribute__((ext_vector_type(4))) float  f32x4;
typedef __attribute__((ext_vector_type(8))) __bf16 bf16x8;

#define DEVI static __device__ __forceinline__
#define BARRIER asm volatile("s_barrier" ::: "memory")

DEVI short f2bf(float f) {  // f32 -> bf16 (RNE)
  unsigned u = __builtin_bit_cast(unsigned, f);
  u = (u + 0x7FFFu + ((u >> 16) & 1u)) >> 16;
  return (short)u;
}

DEVI fx4 mfma16(sx8 a, sx8 b, fx4 c) {
  return __builtin_amdgcn_mfma_f32_16x16x32_bf16(
      __builtin_bit_cast(bf16x8, a), __builtin_bit_cast(bf16x8, b), c, 0, 0, 0);
}

DEVI void gl_lds16(const void* g, void* l) {  // async global->LDS, 16B/lane
  __builtin_amdgcn_global_load_lds(
      (const __attribute__((address_space(1))) void*)g,
      (__attribute__((address_space(3))) void*)l, 16, 0, 0);
}

// ---------------- elementwise f32 -> bf16 cast (vectorized) ----------------
__global__ __launch_bounds__(256) void cast_bf16(const float* __restrict__ in,
                                                 short* __restrict__ out, int n4) {
  int i = blockIdx.x * blockDim.x + threadIdx.x;
  if (i < n4) {
    f32x4 v = *(const f32x4*)&in[(size_t)i * 4];
    sx4 o;
#pragma unroll
    for (int j = 0; j < 4; ++j) o[j] = f2bf(v[j]);
    *(sx4*)&out[(size_t)i * 4] = o;
  }
}

// ---------------- transpose + cast: in[R][C] f32 -> out[C][R] bf16 ----------
__global__ __launch_bounds__(256) void transpose_bf16(const float* __restrict__ in,
                                                      short* __restrict__ out,
                                                      int R, int C) {
  __shared__ float t[32][33];
  int tx = threadIdx.x & 31, ty = threadIdx.x >> 5;
  int r0 = blockIdx.y * 32, c0 = blockIdx.x * 32;
#pragma unroll
  for (int i = 0; i < 4; ++i)
    t[ty + i * 8][tx] = in[(size_t)(r0 + ty + i * 8) * C + c0 + tx];
  __syncthreads();
#pragma unroll
  for (int i = 0; i < 4; ++i)
    out[(size_t)(c0 + ty + i * 8) * R + r0 + tx] = f2bf(t[tx][ty + i * 8]);
}

// ---------------- QKV GEMM: 256^2 tile, 8-phase (4/K-tile) ------------------
// C[4096][3072] = A[4096][1024] @ Bt[3072][1024]^T. BM=BN=256, BK=64, 16 tiles.
// 512 thr = 8 waves (2M x 4N); wave tile 128x64 = acc[8][4]; per K-tile 4
// phases, each: {ds_read subtile (12/4/8/0 b128 - the 24/tile minimum, operands
// held across phases) ; stage ONE half-tile (2 gl_lds/thr) ; s_barrier ;
// setprio1 ; 16 MFMA (one quadrant) ; setprio0 ; s_barrier}.
// Stage halves: Ah = rows {wm*128+h*64..+63}, Bh = rows {wn*64+h*32..+31};
// schedule q0:Ah1(t+1) q1:Bh1(t+1) q2:Ah0(t+2) q3:Bh0(t+2) - each >=1 barrier
// after the overwritten half's last read (death table verified). Counted
// vmcnt(4) once per K-tile at q3 (covers next tile's 4 halves, leaves 2 in
// flight); vmcnt(0) at t==14 (tail, no younger stages to count past).
// LDS 128KB dbuf -> 1 block/CU. [*][64] 8-slot XOR swizzle (0 conflicts,
// verified R8-R10); gl_lds linear dest + pre-swizzled global source.
__global__ __launch_bounds__(512, 2) void gemm_qkv(
    const short* __restrict__ A, const short* __restrict__ Bt,
    const float* __restrict__ bias, short* __restrict__ Qg,
    short* __restrict__ Kg, short* __restrict__ Vtg) {
  __shared__ __align__(16) short As[2][256][64];  // 64 KB
  __shared__ __align__(16) short Bs[2][256][64];  // 64 KB
  const int tid = threadIdx.x, lane = tid & 63, w = tid >> 6;
  const int bid = blockIdx.x;
  const int x = bid & 7, k = bid >> 3;            // XCD id, local idx 0..23
  const int bm = (x & 3) * 4 + (k & 3);           // 0..15
  const int bn = (x >> 2) * 6 + (k >> 2);         // 0..11
  const int wm = w >> 2, wn = w & 3;              // wave tile 128 x 64
  const int c0 = lane & 15, g = lane >> 4;
  const int lr8 = lane >> 3, ls8 = (lane & 7) ^ lr8;
  const int K = 1024;
  const int sw = c0 & 7;                          // read-swizzle row bits
  fx4 acc[8][4] = {};

  auto SA = [&](int h, int u) {  // stage A-half h of K-tile u (2 gl_lds/thr)
    if (u > 15) return;
    const int bf = u & 1;
#pragma unroll
    for (int i = 0; i < 2; ++i) {
      int ch = w * 2 + i;                          // 0..15
      int r = (ch >> 3) * 128 + h * 64 + (ch & 7) * 8;
      gl_lds16(&A[(size_t)(bm * 256 + r + lr8) * K + u * 64 + ls8 * 8],
               &As[bf][r][0]);
    }
  };
  auto SB = [&](int h, int u) {  // stage B-half h of K-tile u
    if (u > 15) return;
    const int bf = u & 1;
#pragma unroll
    for (int i = 0; i < 2; ++i) {
      int ch = w * 2 + i;
      int r = (ch >> 2) * 64 + h * 32 + (ch & 3) * 8;
      gl_lds16(&Bt[(size_t)(bn * 256 + r + lr8) * K + u * 64 + ls8 * 8],
               &Bs[bf][r][0]);
    }
  };

  // prologue: halves that steady-state staged during tiles -2/-1
  SA(0, 0); SB(0, 0); SA(1, 0); SB(1, 0); SA(0, 1); SB(0, 1);
  asm volatile("s_waitcnt vmcnt(0)" ::: "memory");
  BARRIER;

  sx8 af[4][2], bfr[4][2];
  for (int t = 0; t < 16; ++t) {
    const int bf = t & 1;
    // -- q0: read A-h0 (8) + B n0,n1 (4); stage Ah1(t+1); MFMA acc[0..3][0..1]
#pragma unroll
    for (int mi = 0; mi < 4; ++mi) {
      int r = wm * 128 + mi * 16 + c0;
#pragma unroll
      for (int kk = 0; kk < 2; ++kk)
        af[mi][kk] = *(const sx8*)&As[bf][r][(((kk << 2) | g) ^ sw) * 8];
    }
#pragma unroll
    for (int n = 0; n < 2; ++n) {
      int r = wn * 64 + n * 16 + c0;
#pragma unroll
      for (int kk = 0; kk < 2; ++kk)
        bfr[n][kk] = *(const sx8*)&Bs[bf][r][(((kk << 2) | g) ^ sw) * 8];
    }
    SA(1, t + 1);
    BARRIER;
    __builtin_amdgcn_s_setprio(1);
#pragma unroll
    for (int kk = 0; kk < 2; ++kk)
#pragma unroll
      for (int mi = 0; mi < 4; ++mi)
#pragma unroll
        for (int n = 0; n < 2; ++n)
          acc[mi][n] = mfma16(af[mi][kk], bfr[n][kk], acc[mi][n]);
    __builtin_amdgcn_s_setprio(0);
    BARRIER;
    // -- q1: read B n2,n3 (4); stage Bh1(t+1); MFMA acc[0..3][2..3]
#pragma unroll
    for (int n = 2; n < 4; ++n) {
      int r = wn * 64 + n * 16 + c0;
#pragma unroll
      for (int kk = 0; kk < 2; ++kk)
        bfr[n][kk] = *(const sx8*)&Bs[bf][r][(((kk << 2) | g) ^ sw) * 8];
    }
    SB(1, t + 1);
    BARRIER;
    __builtin_amdgcn_s_setprio(1);
#pragma unroll
    for (int kk = 0; kk < 2; ++kk)
#pragma unroll
      for (int mi = 0; mi < 4; ++mi)
#pragma unroll
        for (int n = 2; n < 4; ++n)
          acc[mi][n] = mfma16(af[mi][kk], bfr[n][kk], acc[mi][n]);
    __builtin_amdgcn_s_setprio(0);
    BARRIER;
    // -- q2: read A-h1 (8); stage Ah0(t+2); MFMA acc[4..7][2..3]
#pragma unroll
    for (int mi = 0; mi < 4; ++mi) {
      int r = wm * 128 + 64 + mi * 16 + c0;
#pragma unroll
      for (int kk = 0; kk < 2; ++kk)
        af[mi][kk] = *(const sx8*)&As[bf][r][(((kk << 2) | g) ^ sw) * 8];
    }
    SA(0, t + 2);
    BARRIER;
    __builtin_amdgcn_s_setprio(1);
#pragma unroll
    for (int kk = 0; kk < 2; ++kk)
#pragma unroll
      for (int mi = 0; mi < 4; ++mi)
#pragma unroll
        for (int n = 2; n < 4; ++n)
          acc[4 + mi][n] = mfma16(af[mi][kk], bfr[n][kk], acc[4 + mi][n]);
    __builtin_amdgcn_s_setprio(0);
    BARRIER;
    // -- q3: stage Bh0(t+2); boundary vmcnt; MFMA acc[4..7][0..1]
    SB(0, t + 2);
    if (t < 14) {
      asm volatile("s_waitcnt vmcnt(4)" ::: "memory");
    } else if (t == 14) {
      asm volatile("s_waitcnt vmcnt(0)" ::: "memory");
    }
    BARRIER;
    __builtin_amdgcn_s_setprio(1);
#pragma unroll
    for (int kk = 0; kk < 2; ++kk)
#pragma unroll
      for (int mi = 0; mi < 4; ++mi)
#pragma unroll
        for (int n = 0; n < 2; ++n)
          acc[4 + mi][n] = mfma16(af[mi][kk], bfr[n][kk], acc[4 + mi][n]);
    __builtin_amdgcn_s_setprio(0);
    BARRIER;
  }

  // scatter epilogue (C/D frag layout: row = g*4 + r, col = c0) — verified R11/12
  const float SCALE_Q = 0.125f * 1.4426950408889634f;
#pragma unroll
  for (int m = 0; m < 8; ++m) {
#pragma unroll
    for (int n = 0; n < 4; ++n) {
      int col = bn * 256 + wn * 64 + n * 16 + c0;
      int row0 = bm * 256 + wm * 128 + m * 16 + g * 4;
      float bv = bias[col];
      int b = row0 >> 10, s0 = row0 & 1023;
      if (col < 1024) {
        int h = col >> 6, d = col & 63;
        size_t base = ((size_t)(b * 16 + h) * 1024) * 64 + d;
#pragma unroll
        for (int r = 0; r < 4; ++r)
          Qg[base + (size_t)(s0 + r) * 64] = f2bf((acc[m][n][r] + bv) * SCALE_Q);
      } else if (col < 2048) {
        int c = col - 1024, h = c >> 6, d = c & 63;
        size_t base = ((size_t)(b * 16 + h) * 1024) * 64 + d;
#pragma unroll
        for (int r = 0; r < 4; ++r)
          Kg[base + (size_t)(s0 + r) * 64] = f2bf(acc[m][n][r] + bv);
      } else {
        int c = col - 2048, h = c >> 6, d = c & 63;
        sx4 v;
#pragma unroll
        for (int r = 0; r < 4; ++r) v[r] = f2bf(acc[m][n][r] + bv);
        *(sx4*)&Vtg[((size_t)(b * 16 + h) * 64 + d) * 1024 + s0] = v;
      }
    }
  }
}

// ---------------- proj GEMM: 128^2 tile, 2-phase (unchanged) ----------------
__global__ __launch_bounds__(512, 4) void gemm_proj(
    const short* __restrict__ A, const short* __restrict__ Bt,
    const float* __restrict__ bias, const float* __restrict__ aw,
    const float* __restrict__ ab, float* __restrict__ Out) {
  __shared__ __align__(16) short As[2][128][64];  // 32 KB
  __shared__ __align__(16) short Bs[2][128][64];  // 32 KB
  const int tid = threadIdx.x, lane = tid & 63, w = tid >> 6;
  const int bid = blockIdx.x;
  const int x = bid & 7, k = bid >> 3;
  const int bn = x, bm = k;  // nbn=8: one bn column per XCD
  const int wm = w >> 2, wn = w & 3;
  const int c0 = lane & 15, g = lane >> 4;
  const int lr8 = lane >> 3, ls8 = (lane & 7) ^ lr8;
  const int K = 1024, N = 1024;
  fx4 acc[4][2] = {};

  auto STAGE = [&](int bf, int kt) {
#pragma unroll
    for (int i = 0; i < 2; ++i) {
      int idx = w * 2 + i;
      gl_lds16(&A[(size_t)(bm * 128 + idx * 8 + lr8) * K + kt + ls8 * 8],
               &As[bf][idx * 8][0]);
      gl_lds16(&Bt[(size_t)(bn * 128 + idx * 8 + lr8) * K + kt + ls8 * 8],
               &Bs[bf][idx * 8][0]);
    }
  };

  STAGE(0, 0);
  for (int t = 0; t < 16; ++t) {
    const int bf = t & 1;
    if (t + 1 < 16) {
      STAGE(bf ^ 1, (t + 1) * 64);
      asm volatile("s_waitcnt vmcnt(4)" ::: "memory");
    } else {
      asm volatile("s_waitcnt vmcnt(0)" ::: "memory");
    }
    BARRIER;
    __builtin_amdgcn_s_setprio(1);
#pragma unroll
    for (int kk = 0; kk < 2; ++kk) {
      sx8 af[4], bfr[2];
      int sb = kk * 4 + g;
#pragma unroll
      for (int m = 0; m < 4; ++m) {
        int row = wm * 64 + m * 16 + c0;
        af[m] = *(const sx8*)&As[bf][row][(sb ^ (row & 7)) * 8];
      }
#pragma unroll
      for (int n = 0; n < 2; ++n) {
        int row = wn * 32 + n * 16 + c0;
        bfr[n] = *(const sx8*)&Bs[bf][row][(sb ^ (row & 7)) * 8];
      }
#pragma unroll
      for (int m = 0; m < 4; ++m)
#pragma unroll
        for (int n = 0; n < 2; ++n) acc[m][n] = mfma16(af[m], bfr[n], acc[m][n]);
    }
    __builtin_amdgcn_s_setprio(0);
    BARRIER;
  }

#pragma unroll
  for (int m = 0; m < 4; ++m) {
#pragma unroll
    for (int n = 0; n < 2; ++n) {
      int col = bn * 128 + wn * 32 + n * 16 + c0;
      int row0 = bm * 128 + wm * 64 + m * 16 + g * 4;
      float bv = bias[col], wv = aw[col], av = ab[col];
#pragma unroll
      for (int r = 0; r < 4; ++r)
        Out[(size_t)(row0 + r) * N + col] = (acc[m][n][r] + bv) * wv + av;
    }
  }
}

// ---------------- flash attention (causal), LDS-staged K/V ------------------
__global__ __launch_bounds__(256, 4) void attn_kernel(const short* __restrict__ Qg,
                                                      const short* __restrict__ Kg,
                                                      const short* __restrict__ Vtg,
                                                      short* __restrict__ AO) {
  __shared__ __align__(16) short Ks[2][64][64];   // 16 KB
  __shared__ __align__(16) short Vts[2][64][64];  // 16 KB
  __shared__ __align__(16) short Ps[4][16 * 64];  // 8 KB
  const int tid = threadIdx.x, lane = tid & 63, w = tid >> 6;
  const int bid = blockIdx.x;
  const int u = bid >> 8, v = bid & 255, bh = v >> 2, jj = v & 3;
  const int qt = (u == 0) ? jj : (u == 1) ? 7 - jj : (u == 2) ? 8 + jj : 15 - jj;
  const int b = bh >> 4, h = bh & 15;
  const int c0 = lane & 15, g = lane >> 4;
  const int lr8 = lane >> 3, ls8 = (lane & 7) ^ lr8;
  const int q0 = qt * 64 + w * 16;
  const short* Qp = Qg + (size_t)bh * 65536;
  const short* Kp = Kg + (size_t)bh * 65536;
  const short* Vp = Vtg + (size_t)bh * 65536;
  short* pbase = &Ps[w][0];
  const int s8 = (c0 & 7) * 8;  // P swizzle

  sx8 qf[2];
#pragma unroll
  for (int kk = 0; kk < 2; ++kk)
    qf[kk] = *(const sx8*)&Qp[(size_t)(q0 + c0) * 64 + kk * 32 + g * 8];

  fx4 o[4] = {};
  float mrun = -1e30f, lrun = 0.f;
  const int q_glob = q0 + c0;

  auto STAGE = [&](int bf, int kv0) {
#pragma unroll
    for (int i = 0; i < 2; ++i) {
      int idx = w * 2 + i;
      gl_lds16(&Kp[(size_t)(kv0 + idx * 8 + lr8) * 64 + ls8 * 8], &Ks[bf][idx * 8][0]);
    }
#pragma unroll
    for (int i = 0; i < 2; ++i) {
      int idx = w * 2 + i;
      gl_lds16(&Vp[(size_t)(idx * 8 + lr8) * 1024 + kv0 + ls8 * 8], &Vts[bf][idx * 8][0]);
    }
  };

  STAGE(0, 0);
  for (int t = 0; t <= qt; ++t) {
    const int kv0 = t * 64;
    const int bf = t & 1;
    const bool more = t < qt;
    if (more) {
      STAGE(bf ^ 1, kv0 + 64);
      asm volatile("s_waitcnt vmcnt(4)" ::: "memory");
    } else {
      asm volatile("s_waitcnt vmcnt(0)" ::: "memory");
    }
    BARRIER;

    fx4 st[4];
    __builtin_amdgcn_s_setprio(1);
#pragma unroll
    for (int mf = 0; mf < 4; ++mf) {
      int row = mf * 16 + c0;
      sx8 kf0 = *(const sx8*)&Ks[bf][row][(g ^ (row & 7)) * 8];
      sx8 kf1 = *(const sx8*)&Ks[bf][row][((4 + g) ^ (row & 7)) * 8];
      fx4 z = {0.f, 0.f, 0.f, 0.f};
      z = mfma16(kf0, qf[0], z);
      st[mf] = mfma16(kf1, qf[1], z);
    }
    __builtin_amdgcn_s_setprio(0);

    float pmax = -1e30f;
    if (t == qt) {
#pragma unroll
      for (int mf = 0; mf < 4; ++mf)
#pragma unroll
        for (int r = 0; r < 4; ++r) {
          int kv = kv0 + mf * 16 + g * 4 + r;
          float z = (kv > q_glob) ? -1e30f : st[mf][r];
          st[mf][r] = z;
          pmax = fmaxf(pmax, z);
        }
    } else {
#pragma unroll
      for (int mf = 0; mf < 4; ++mf)
#pragma unroll
        for (int r = 0; r < 4; ++r) pmax = fmaxf(pmax, st[mf][r]);
    }
    pmax = fmaxf(pmax, __shfl_xor(pmax, 16));
    pmax = fmaxf(pmax, __shfl_xor(pmax, 32));
    float mnew = fmaxf(mrun, pmax);
    float alpha = __builtin_amdgcn_exp2f(mrun - mnew);
    float psum = 0.f;
#pragma unroll
    for (int mf = 0; mf < 4; ++mf) {
      sx4 pv;
#pragma unroll
      for (int r = 0; r < 4; ++r) {
        float pp = __builtin_amdgcn_exp2f(st[mf][r] - mnew);
        psum += pp;
        pv[r] = f2bf(pp);
      }
      *(sx4*)&pbase[c0 * 64 + ((mf * 16 + g * 4) ^ s8)] = pv;
    }
    psum += __shfl_xor(psum, 16);
    psum += __shfl_xor(psum, 32);
    lrun = lrun * alpha + psum;
    mrun = mnew;
#pragma unroll
    for (int mf = 0; mf < 4; ++mf) o[mf] *= alpha;

    __builtin_amdgcn_s_setprio(1);
#pragma unroll
    for (int kk = 0; kk < 2; ++kk) {
      sx8 pbf = *(const sx8*)&pbase[c0 * 64 + ((kk * 32 + g * 8) ^ s8)];
#pragma unroll
      for (int mf = 0; mf < 4; ++mf) {
        int row = mf * 16 + c0;
        sx8 vaf = *(const sx8*)&Vts[bf][row][((kk * 4 + g) ^ (row & 7)) * 8];
        o[mf] = mfma16(vaf, pbf, o[mf]);
      }
    }
    __builtin_amdgcn_s_setprio(0);
    BARRIER;
  }

  float inv = 1.0f / lrun;
  int q = q0 + c0;
#pragma unroll
  for (int mf = 0; mf < 4; ++mf) {
    sx4 v4;
#pragma unroll
    for (int r = 0; r < 4; ++r) v4[r] = f2bf(o[mf][r] * inv);
    int d0 = mf * 16 + g * 4;
    *(sx4*)&AO[((size_t)(b * 1024 + q)) * 1024 + h * 64 + d0] = v4;
  }
}

// ---------------- launch ----------------------------------------------------
extern "C" void kernel_launch(void* const* d_in, const int* in_sizes, int n_in,
                              void* d_out, int out_size, void* d_ws, size_t ws_size,
                              hipStream_t stream) {
  const float* hs  = (const float*)d_in[0];
  const float* caw = (const float*)d_in[1];
  const float* cab = (const float*)d_in[2];
  const float* cpw = (const float*)d_in[3];
  const float* cpb = (const float*)d_in[4];
  const float* afw = (const float*)d_in[5];
  const float* afb = (const float*)d_in[6];
  float* out = (float*)d_out;
  char* ws = (char*)d_ws;

  short* hsb    = (short*)(ws);                       // [4096][1024] bf16
  short* ao     = (short*)(ws);                       // overlaps hsb
  short* wqkvt  = (short*)(ws + ((size_t)8  << 20));  // [3072][1024] bf16
  short* wprojt = (short*)(ws + ((size_t)14 << 20));  // [1024][1024] bf16
  short* Qg     = (short*)(ws + ((size_t)16 << 20));  // [4][16][1024][64]
  short* Kg     = (short*)(ws + ((size_t)24 << 20));  // [4][16][1024][64]
  short* Vtg    = (short*)(ws + ((size_t)32 << 20));  // [4][16][64][1024]

  cast_bf16<<<4096, 256, 0, stream>>>(hs, hsb, 1048576);
  transpose_bf16<<<dim3(96, 32), 256, 0, stream>>>(caw, wqkvt, 1024, 3072);
  transpose_bf16<<<dim3(32, 32), 256, 0, stream>>>(cpw, wprojt, 1024, 1024);
  gemm_qkv<<<192, 512, 0, stream>>>(hsb, wqkvt, cab, Qg, Kg, Vtg);
  attn_kernel<<<1024, 256, 0, stream>>>(Qg, Kg, Vtg, ao);
  gemm_proj<<<256, 512, 0, stream>>>(ao, wprojt, cpb, afw, afb, out);
}